// Round 3
// baseline (132.849 us; speedup 1.0000x reference)
//
#include <hip/hip_runtime.h>

#define NLAYERS 32
#define H 16
#define INDIM 124
#define NT 4   // batch tiles per wave (round 0 had 8; halved to double wave count)

typedef __fp16 pk16x2 __attribute__((ext_vector_type(2)));   // cvt_pkrtz result
typedef _Float16 half4 __attribute__((ext_vector_type(4)));
typedef _Float16 half8 __attribute__((ext_vector_type(8)));
typedef float floatx4 __attribute__((ext_vector_type(4)));
typedef float floatx2 __attribute__((ext_vector_type(2)));
typedef int intx2 __attribute__((ext_vector_type(2)));
typedef int intx4 __attribute__((ext_vector_type(4)));

static __device__ __forceinline__ half4 mk_half4(pk16x2 a, pk16x2 b) {
    intx2 v;
    v.x = __builtin_bit_cast(int, a);
    v.y = __builtin_bit_cast(int, b);
    return __builtin_bit_cast(half4, v);
}
static __device__ __forceinline__ half8 mk_half8(pk16x2 a, pk16x2 b,
                                                 pk16x2 c, pk16x2 d) {
    intx4 v;
    v.x = __builtin_bit_cast(int, a);
    v.y = __builtin_bit_cast(int, b);
    v.z = __builtin_bit_cast(int, c);
    v.w = __builtin_bit_cast(int, d);
    return __builtin_bit_cast(half8, v);
}
static __device__ __forceinline__ half4 low_half(half8 v) {
    intx4 i = __builtin_bit_cast(intx4, v);
    intx2 r; r.x = i.x; r.y = i.y;
    return __builtin_bit_cast(half4, r);
}

// Prep kernel: build the correction A' fragments (hi|lo interleaved Ws^T)
// once into the global workspace.  2048 x half8 = 32 KiB; main-kernel reads
// are L1/L2 hits.  Values bit-identical to round 0's per-block LDS staging.
__global__ void prep_kernel(const float* __restrict__ Ws,
                            half8* __restrict__ wcg) {
    int idx = blockIdx.x * 256 + threadIdx.x;   // 8 blocks x 256 = 2048
    int l = idx >> 6, sl = idx & 63;
    int sq = sl >> 4, scol = sl & 15;
    half8 vc;
#pragma unroll
    for (int j = 0; j < 4; ++j) {
        float w = Ws[l * H * H + (sq * 4 + j) * H + scol];
        _Float16 hi = (_Float16)w;
        vc[j] = hi;                              // slots j<4: hi (pairs hlo)
        vc[j + 4] = (_Float16)(w - (float)hi);   // slots j>=4: lo (pairs hhi)
    }
    wcg[idx] = vc;
}

// Split-f16 MFMA residual MLP.  hT lives in the MFMA D-fragment
// (m=quad*4+r, n=lane&15) == the next MFMA's B-fragment layout.
// Per residual layer: d = MFMA16(wc.lo, hhi, bias) then one K=32 correction
// MFMA with A' = column-interleaved [WThi | WTlo] and B' = {hlo[0:4], hhi[0:4]}.
// leaky(x) = 0.6x + 0.4|x| -> two FMAs.  hlo = h - (h & 0xFFFFE000).
//
// This round vs round 0 (127 us, passing): wc moved LDS->global workspace
// (each lane only ever read its OWN fragment, so LDS sharing bought nothing),
// prefetched 1 layer ahead in a ROLLED loop (unroll 1 keeps the prefetch
// 1-deep so registers don't balloon).  LDS = 4K (w1hi) + 2K (bias) = 6144 B.
// NT 8->4, grid 1024->2048 blocks: 8 blocks/CU x 4 waves = 32 waves/CU
// (was 16), one full-occupancy round.  launch_bounds kept at (256,4) — the
// hard min-8 cap is the prime suspect for rounds 1-2's corruption; the
// compiler chose 64 VGPR on its own at NT=8 under this same bound.
__global__ __launch_bounds__(256, 4) void fractal_kernel(
    const float* __restrict__ z, const float* __restrict__ c,
    const float* __restrict__ W1, const float* __restrict__ b1,
    const float* __restrict__ bs, const float* __restrict__ Wf,
    const float* __restrict__ bf, const half8* __restrict__ wcg,
    float* __restrict__ out, int B)
{
    __shared__ half8 lds_w1hi[4 * 64];       // layer-1 hi A frags
    __shared__ floatx4 lds_bs[NLAYERS * 4];  // bias frags

    const int tid = threadIdx.x;
    const int lane = tid & 63;
    const int q = lane >> 4, col = lane & 15;

    // Stage W1^T hi fragments: A[m=col][k] = W1[k][col], k = t*32 + q*8 + j.
    {
        int t = tid >> 6, sl = tid & 63;
        int sq = sl >> 4, scol = sl & 15;
        half8 vh;
#pragma unroll
        for (int j = 0; j < 8; ++j) {
            int k = t * 32 + sq * 8 + j;
            float w = (k < INDIM) ? W1[k * H + scol] : 0.f;
            vh[j] = (_Float16)w;
        }
        lds_w1hi[tid] = vh;
    }
    for (int idx = tid; idx < NLAYERS * 4; idx += 256) {
        int l = idx >> 2, sq = idx & 3;
        floatx4 v;
#pragma unroll
        for (int j = 0; j < 4; ++j) v[j] = bs[l * H + sq * 4 + j];
        lds_bs[idx] = v;
    }

    // Layer-1 LO fragments live in registers (own lane's fragment only).
    half8 w1lo[4];
#pragma unroll
    for (int t = 0; t < 4; ++t) {
#pragma unroll
        for (int j = 0; j < 8; ++j) {
            int k = t * 32 + q * 8 + j;
            float w = (k < INDIM) ? W1[k * H + col] : 0.f;
            _Float16 hi = (_Float16)w;
            w1lo[t][j] = (_Float16)(w - (float)hi);
        }
    }
    __syncthreads();

    const int wave = (blockIdx.x * 256 + tid) >> 6;
    const int nwaves = (gridDim.x * 256) >> 6;   // 8192
    const int stride16 = nwaves * 16;            // batch stride between tiles

    constexpr float C_HI = 0.15915494309189535f;                        // fl(1/2pi)
    constexpr float C_LO = (float)(0.15915494309189535 - (double)C_HI); // residual

    const floatx2* z2 = (const floatx2*)z;
    const floatx2* c2 = (const floatx2*)c;
    const floatx4 bias1 = *(const floatx4*)(b1 + q * 4);
    const floatx4 wf4 = *(const floatx4*)(Wf + q * 4);
    const float bff = bf[0];

    const int n0 = wave * 16 + col;
    float h[NT][4];   // h[i][r]: master fp32 hidden state for tile i

    // ---- Layer 1: positional encoding + Dense(124->16), groups of 4 ----
    // (verbatim round-0 structure; NT=4 -> one group)
#pragma unroll
    for (int g = 0; g < NT / 4; ++g) {
        float yh[4][4], yl[4][4];   // [tile-in-group][dim]
#pragma unroll
        for (int u = 0; u < 4; ++u) {
            const int n = n0 + (g * 4 + u) * stride16;
            floatx2 zz = z2[n], cc = c2[n];
            float xv[4] = {zz.x, zz.y, cc.x, cc.y};
            // two-float x/(2pi): x*2^i exact in fp32, so frac((yh+yl)*2^i)
            // gives an accurate phase for sin(x*2^i) without Payne-Hanek.
#pragma unroll
            for (int d = 0; d < 4; ++d) {
                yh[u][d] = xv[d] * C_HI;
                yl[u][d] = __builtin_fmaf(xv[d], C_HI, -yh[u][d]) + xv[d] * C_LO;
            }
            // raw features x_d needed later (t=0 cos slots, q==0); stash in h[].
#pragma unroll
            for (int r = 0; r < 4; ++r) h[g * 4 + u][r] = xv[r];
        }
        floatx4 acc[4] = {bias1, bias1, bias1, bias1};
#pragma unroll
        for (int t = 0; t < 4; ++t) {
            // features k = t*32 + q*8 + j: j<4 -> cos(2^(t*4+q-1) x_d),
            // j>=4 -> sin(2^(t*4+q) x_d), d=j&3; t=0,q=0,j<4 -> raw x.
            // k=124..127 hit zeroed A columns — values harmless.
            const float sc_cos = __builtin_ldexpf(1.0f, t * 4 + q - 1);
            const float sc_sin = __builtin_ldexpf(1.0f, t * 4 + q);
            half8 ah = lds_w1hi[t * 64 + lane];   // shared across 4 tiles
            half8 al = w1lo[t];
#pragma unroll
            for (int u = 0; u < 4; ++u) {
                float fv[8];
#pragma unroll
                for (int j = 0; j < 8; ++j) {
                    const int d = j & 3;
                    const bool is_cos = (j < 4);
                    const float sc = is_cos ? sc_cos : sc_sin;
                    float fr = __builtin_amdgcn_fractf(yh[u][d] * sc);
                    fr = __builtin_fmaf(yl[u][d], sc, fr);
                    if (is_cos) fr += 0.25f;             // cos = sin(+1/4 rev)
                    fv[j] = __builtin_amdgcn_sinf(fr);
                    if (t == 0 && is_cos && q == 0) fv[j] = h[g * 4 + u][j];
                }
                half8 bh = mk_half8(__builtin_amdgcn_cvt_pkrtz(fv[0], fv[1]),
                                    __builtin_amdgcn_cvt_pkrtz(fv[2], fv[3]),
                                    __builtin_amdgcn_cvt_pkrtz(fv[4], fv[5]),
                                    __builtin_amdgcn_cvt_pkrtz(fv[6], fv[7]));
                acc[u] = __builtin_amdgcn_mfma_f32_16x16x32_f16(ah, bh, acc[u], 0, 0, 0);
                acc[u] = __builtin_amdgcn_mfma_f32_16x16x32_f16(al, bh, acc[u], 0, 0, 0);
            }
        }
#pragma unroll
        for (int u = 0; u < 4; ++u)
#pragma unroll
            for (int r = 0; r < 4; ++r)
                h[g * 4 + u][r] = fmaxf(acc[u][r], 0.2f * acc[u][r]);
    }

    // ---- 32 residual layers, NT tiles interleaved; wc prefetched 1 layer
    // ahead from the global table (L1/L2-resident 32 KiB).  Rolled loop
    // (unroll 1) keeps the prefetch exactly 1-deep -> low register pressure.
    const half8* wlane = wcg + lane;
    half8 wc_next = wlane[0];
#pragma unroll 1
    for (int l = 0; l < NLAYERS; ++l) {
        half8 wc = wc_next;
        wc_next = wlane[((l + 1) & (NLAYERS - 1)) * 64];  // wraps at l=31; harmless
        half4 wh = low_half(wc);          // == hi(Ws^T) fragment, free extract
        floatx4 bias = lds_bs[l * 4 + q];

#pragma unroll
        for (int i = 0; i < NT; ++i) {
            // hi = f16_rtz(h); float(hi) == h & 0xFFFFE000 for normal h.
            half4 hhi = mk_half4(__builtin_amdgcn_cvt_pkrtz(h[i][0], h[i][1]),
                                 __builtin_amdgcn_cvt_pkrtz(h[i][2], h[i][3]));
            float lo[4];
#pragma unroll
            for (int r = 0; r < 4; ++r) {
                unsigned u = __builtin_bit_cast(unsigned, h[i][r]) & 0xFFFFE000u;
                lo[r] = h[i][r] - __builtin_bit_cast(float, u);
            }
            intx2 hbits = __builtin_bit_cast(intx2, hhi);
            half8 bp = mk_half8(__builtin_amdgcn_cvt_pkrtz(lo[0], lo[1]),
                                __builtin_amdgcn_cvt_pkrtz(lo[2], lo[3]),
                                __builtin_bit_cast(pk16x2, hbits.x),
                                __builtin_bit_cast(pk16x2, hbits.y));
            floatx4 d = __builtin_amdgcn_mfma_f32_16x16x16f16(wh, hhi, bias, 0, 0, 0);
            d = __builtin_amdgcn_mfma_f32_16x16x32_f16(wc, bp, d, 0, 0, 0);
#pragma unroll
            for (int r = 0; r < 4; ++r) {
                // h += leaky(d) = 0.6d + 0.4|d|
                h[i][r] = __builtin_fmaf(0.6f, d[r], h[i][r]);
                h[i][r] = __builtin_fmaf(0.4f, __builtin_fabsf(d[r]), h[i][r]);
            }
        }
    }

    // ---- Final Dense(16->1): column n spread over 4 quads ----
#pragma unroll
    for (int i = 0; i < NT; ++i) {
        float p = h[i][0] * wf4.x;
        p = __builtin_fmaf(h[i][1], wf4.y, p);
        p = __builtin_fmaf(h[i][2], wf4.z, p);
        p = __builtin_fmaf(h[i][3], wf4.w, p);
        p += __shfl_xor(p, 16, 64);
        p += __shfl_xor(p, 32, 64);
        if (q == 0) out[n0 + i * stride16] = p + bff;
    }
}

extern "C" void kernel_launch(void* const* d_in, const int* in_sizes, int n_in,
                              void* d_out, int out_size, void* d_ws, size_t ws_size,
                              hipStream_t stream) {
    const float* z  = (const float*)d_in[0];
    const float* c  = (const float*)d_in[1];
    const float* W1 = (const float*)d_in[2];
    const float* b1 = (const float*)d_in[3];
    const float* Ws = (const float*)d_in[4];
    const float* bs = (const float*)d_in[5];
    const float* Wf = (const float*)d_in[6];
    const float* bf = (const float*)d_in[7];
    const int B = in_sizes[0] / 2;  // z is (B,2)

    half8* wcg = (half8*)d_ws;                  // 2048 x 16 B = 32 KiB
    prep_kernel<<<8, 256, 0, stream>>>(Ws, wcg);

    const int blocks = 2048;  // 8192 waves x 4 tiles x 16 = 524288 samples
    fractal_kernel<<<blocks, 256, 0, stream>>>(z, c, W1, b1, bs, Wf, bf,
                                               wcg, (float*)d_out, B);
}